// Round 6
// baseline (285.654 us; speedup 1.0000x reference)
//
#include <hip/hip_runtime.h>
#include <cmath>

// Tree constants (complete 4-ary tree, depth 7)
constexpr int N_NODES = 21845;
constexpr int N_INT   = 5461;   // internal nodes (levels 0..6)
constexpr int HID     = 512;

typedef short  short8  __attribute__((ext_vector_type(8)));
typedef float  floatx4 __attribute__((ext_vector_type(4)));

// fp32 -> bf16 bit pattern, round-to-nearest-even
__device__ __forceinline__ unsigned short f2bf(float f) {
    unsigned int u = __float_as_uint(f);
    u += 0x7fffu + ((u >> 16) & 1u);
    return (unsigned short)(u >> 16);
}

#define GLD_LDS(g, l) __builtin_amdgcn_global_load_lds( \
    (const __attribute__((address_space(1))) void*)(g), \
    (__attribute__((address_space(3))) void*)(l), 16, 0, 0)

// ================= grid barrier (SMALL grids only) =================
// Rounds 2-4: full-grid (~1000-block) barriers cost ~35us regardless of arrival/
// detection structure (per-leader L2 cache-maintenance). At <=64 blocks the same
// barrier is a few us — cheaper than a dispatch boundary (~5-7us under graph replay).
// Round 5: p56_kernel (64-block grid_bar) validated this regime.
__device__ __forceinline__ void grid_bar(unsigned* bars, unsigned phase) {
    __syncthreads();
    if (threadIdx.x == 0) {
        const unsigned g   = blockIdx.x & 31;
        const unsigned gsz = gridDim.x >> 5;          // NB is a multiple of 32
        unsigned* gcnt  = bars + g * 32;
        unsigned* gflag = bars + 1024 + g * 32;
        unsigned r = __hip_atomic_fetch_add(gcnt, 1u, __ATOMIC_ACQ_REL, __HIP_MEMORY_SCOPE_AGENT);
        if (r == phase * gsz - 1u) {
            unsigned rr = __hip_atomic_fetch_add(bars + 2048, 1u, __ATOMIC_ACQ_REL,
                                                 __HIP_MEMORY_SCOPE_AGENT);
            if (rr == phase * 32u - 1u) {
                __builtin_amdgcn_fence(__ATOMIC_RELEASE, "agent");
                #pragma unroll
                for (int i = 0; i < 32; ++i)
                    __hip_atomic_store(bars + 1024 + i * 32, phase, __ATOMIC_RELAXED,
                                       __HIP_MEMORY_SCOPE_AGENT);
            }
        }
        while (__hip_atomic_load(gflag, __ATOMIC_RELAXED, __HIP_MEMORY_SCOPE_AGENT) < phase)
            __builtin_amdgcn_s_sleep(2);
        __builtin_amdgcn_fence(__ATOMIC_ACQUIRE, "agent");
    }
    __syncthreads();
}

// 16-block sub-barrier (blocks 0..15 only) — validated rounds 3-5
__device__ __forceinline__ void tail_bar(unsigned* bars, unsigned phase) {
    __syncthreads();
    if (threadIdx.x == 0) {
        unsigned* cnt  = bars + 2080;
        unsigned* flag = bars + 2112;
        unsigned r = __hip_atomic_fetch_add(cnt, 1u, __ATOMIC_ACQ_REL, __HIP_MEMORY_SCOPE_AGENT);
        if (r == phase * 16u - 1u)
            __hip_atomic_store(flag, phase, __ATOMIC_RELEASE, __HIP_MEMORY_SCOPE_AGENT);
        while (__hip_atomic_load(flag, __ATOMIC_RELAXED, __HIP_MEMORY_SCOPE_AGENT) < phase)
            __builtin_amdgcn_s_sleep(2);
        __builtin_amdgcn_fence(__ATOMIC_ACQUIRE, "agent");
    }
    __syncthreads();
}

// ================= prep: zero leaf h/c (67 MB) + cast all GEMM operands to bf16 ==========
// MUST run on a WIDE grid: round-5 measured streaming writes at only ~0.7 TB/s on a
// 256-block grid (101us tail); this exact kernel at grid 2048 was <52us in round 0.
__device__ __forceinline__ void prep_body(const float* __restrict__ x,
                                          const float* __restrict__ W_iou,
                                          const float* __restrict__ W_f,
                                          const float* __restrict__ U_iou,
                                          const float* __restrict__ U_f,
                                          float* __restrict__ h_leaf,
                                          float* __restrict__ c_leaf,
                                          unsigned short* __restrict__ dstb)
{
    const size_t Z  = (size_t)(N_NODES - N_INT) * HID / 4;
    const size_t C0 = (size_t)N_INT * 512 / 4;
    const size_t C1 = C0 + 1536 * 512 / 4;
    const size_t C2 = C1 + 512 * 512 / 4;
    const size_t C3 = C2 + 1536 * 512 / 4;
    const size_t C4 = C3 + 512 * 512 / 4;
    const size_t total = 2 * Z + C4;
    size_t i = (size_t)blockIdx.x * blockDim.x + threadIdx.x;
    const size_t stride = (size_t)gridDim.x * blockDim.x;
    const float4 zz = {0.f, 0.f, 0.f, 0.f};
    for (; i < total; i += stride) {
        if (i < 2 * Z) {
            if (i < Z) ((float4*)h_leaf)[i] = zz;
            else       ((float4*)c_leaf)[i - Z] = zz;
        } else {
            size_t k = i - 2 * Z;
            const float* src; size_t off;
            if (k < C0)      { src = x;     off = k; }
            else if (k < C1) { src = W_iou; off = k - C0; }
            else if (k < C2) { src = W_f;   off = k - C1; }
            else if (k < C3) { src = U_iou; off = k - C2; }
            else             { src = U_f;   off = k - C3; }
            float4 v = ((const float4*)src)[off];
            ushort4 o;
            o.x = f2bf(v.x); o.y = f2bf(v.y); o.z = f2bf(v.z); o.w = f2bf(v.w);
            ((ushort4*)dstb)[k] = o;
        }
    }
}

__global__ void prep_kernel(const float* __restrict__ x,
                            const float* __restrict__ W_iou,
                            const float* __restrict__ W_f,
                            const float* __restrict__ U_iou,
                            const float* __restrict__ U_f,
                            float* __restrict__ h_leaf,
                            float* __restrict__ c_leaf,
                            unsigned short* __restrict__ dstb)
{
    prep_body(x, W_iou, W_f, U_iou, U_f, h_leaf, c_leaf, dstb);
}

// ================= 128x128 bf16 MFMA GEMM tile (K=512), m97-style =================
__device__ __forceinline__ void gemm_tile_128(
    const unsigned short* __restrict__ A, int Arows,
    const unsigned short* __restrict__ B,
    const float* __restrict__ bias,
    float* __restrict__ C, int ldc,
    int bm, int bn)
{
    __shared__ short8 AsV[1024];   // 128 rows x 8 chunks (16B) = 16 KB
    __shared__ short8 BsV[1024];

    const int tid  = threadIdx.x;
    const int wave = tid >> 6;
    const int lane = tid & 63;
    const int quad = lane >> 4;
    const int lr   = lane & 15;
    const int wr = (wave >> 1) * 64;
    const int wc = (wave & 1) * 64;

    floatx4 acc[4][4];
    #pragma unroll
    for (int i = 0; i < 4; ++i)
        #pragma unroll
        for (int j = 0; j < 4; ++j)
            acc[i][j] = (floatx4){0.f, 0.f, 0.f, 0.f};

    int s_row[4], s_gk[4];
    #pragma unroll
    for (int it = 0; it < 4; ++it) {
        int c = it * 256 + wave * 64 + lane;
        s_row[it] = c >> 3;
        s_gk[it]  = (c & 7) ^ (s_row[it] & 7);
    }

    for (int k0 = 0; k0 < 512; k0 += 64) {
        #pragma unroll
        for (int it = 0; it < 4; ++it) {
            int row = s_row[it];
            int gm = bm + row; if (gm >= Arows) gm = Arows - 1;
            GLD_LDS(A + (size_t)gm * 512 + k0 + s_gk[it] * 8, &AsV[it * 256 + wave * 64]);
            int gn = bn + row;
            GLD_LDS(B + (size_t)gn * 512 + k0 + s_gk[it] * 8, &BsV[it * 256 + wave * 64]);
        }
        __syncthreads();

        #pragma unroll
        for (int kc = 0; kc < 2; ++kc) {
            short8 af[4], bfr[4];
            const int q = kc * 4 + quad;
            #pragma unroll
            for (int mt = 0; mt < 4; ++mt) {
                int row = wr + mt * 16 + lr;
                af[mt] = AsV[row * 8 + (q ^ (row & 7))];
            }
            #pragma unroll
            for (int nt = 0; nt < 4; ++nt) {
                int row = wc + nt * 16 + lr;
                bfr[nt] = BsV[row * 8 + (q ^ (row & 7))];
            }
            #pragma unroll
            for (int mt = 0; mt < 4; ++mt)
                #pragma unroll
                for (int nt = 0; nt < 4; ++nt)
                    acc[mt][nt] = __builtin_amdgcn_mfma_f32_16x16x32_bf16(
                        af[mt], bfr[nt], acc[mt][nt], 0, 0, 0);
        }
        __syncthreads();
    }

    #pragma unroll
    for (int mt = 0; mt < 4; ++mt) {
        #pragma unroll
        for (int r = 0; r < 4; ++r) {
            int gm = bm + wr + mt * 16 + quad * 4 + r;
            if (gm >= Arows) continue;
            #pragma unroll
            for (int nt = 0; nt < 4; ++nt) {
                int gn = bn + wc + nt * 16 + lr;
                float v = acc[mt][nt][r];
                if (bias) v += bias[gn];
                C[(size_t)gm * ldc + gn] = v;
            }
        }
    }
}

// ================= direct-from-global MFMA GEMM for tiny levels =================
__device__ __forceinline__ void direct_tile_16x64(
    const unsigned short* __restrict__ A, int Arows,
    const unsigned short* __restrict__ B,
    float* __restrict__ C, int ldc,
    int m0, int n0)
{
    const int lane = threadIdx.x & 63;
    const int quad = lane >> 4;
    const int lr   = lane & 15;
    int am = m0 + lr; if (am >= Arows) am = Arows - 1;   // clamp (store-masked)
    const unsigned short* ap = A + (size_t)am * 512 + quad * 8;
    const unsigned short* bp = B + (size_t)(n0 + lr) * 512 + quad * 8;

    floatx4 acc[4];
    #pragma unroll
    for (int j = 0; j < 4; ++j) acc[j] = (floatx4){0.f, 0.f, 0.f, 0.f};

    #pragma unroll
    for (int k0 = 0; k0 < 512; k0 += 32) {
        short8 af = *(const short8*)(ap + k0);
        #pragma unroll
        for (int j = 0; j < 4; ++j) {
            short8 bf = *(const short8*)(bp + (size_t)j * 16 * 512 + k0);
            acc[j] = __builtin_amdgcn_mfma_f32_16x16x32_bf16(af, bf, acc[j], 0, 0, 0);
        }
    }

    #pragma unroll
    for (int j = 0; j < 4; ++j) {
        #pragma unroll
        for (int r = 0; r < 4; ++r) {
            int gm = m0 + quad * 4 + r;
            if (gm < Arows) C[(size_t)gm * ldc + n0 + j * 16 + lr] = acc[j][r];
        }
    }
}

// ================= small-level U-GEMMs (grid-stride over 16x64 wave tiles) =================
__device__ __forceinline__ void small_gemm_phase(
    const unsigned short* __restrict__ hs_bf,
    const unsigned short* __restrict__ hch_bf,
    const unsigned short* __restrict__ Uib, const unsigned short* __restrict__ Ufb,
    float* __restrict__ ioud, float* __restrict__ fd, int nl, int nbsub)
{
    const int mI = (nl + 15) >> 4;
    const int mF = (4 * nl + 15) >> 4;
    const int totW = mI * 24 + mF * 8;
    for (int w = blockIdx.x * 4 + (threadIdx.x >> 6); w < totW; w += nbsub * 4) {
        if (w < mI * 24)
            direct_tile_16x64(hs_bf, nl, Uib, ioud, 1536, (w / 24) * 16, (w % 24) * 64);
        else {
            int w2 = w - mI * 24;
            direct_tile_16x64(hch_bf, 4 * nl, Ufb, fd, 512, (w2 / 8) * 16, (w2 % 8) * 64);
        }
    }
}

// ================= 256-thread combine: 4 siblings/parent group, 8 hid elems/thread ========
__device__ void combine_level_256(
    const float* __restrict__ wx_iou, const float* __restrict__ wx_f,
    const float* __restrict__ ioud, const float* __restrict__ fd,
    const float* __restrict__ c_child,
    float* __restrict__ h_out, float* __restrict__ c_out,
    unsigned short* __restrict__ h_bf, unsigned short* __restrict__ hs_bf,
    int s, int np, int hasU, int nbsub)
{
    __shared__ floatx4 hsbuf[512];   // 8 KB
    const int k  = threadIdx.x >> 6;
    const int jg = threadIdx.x & 63;
    const int j8 = jg << 3;

    for (int tp = blockIdx.x; tp < np; tp += nbsub) {
        const int t = 4 * tp + k;
        const int n = s + t;
        const float* wrow = wx_iou + (size_t)n * 1536 + j8;
        floatx4 iv0 = *(const floatx4*)(wrow);
        floatx4 iv1 = *(const floatx4*)(wrow + 4);
        floatx4 ov0 = *(const floatx4*)(wrow + 512);
        floatx4 ov1 = *(const floatx4*)(wrow + 516);
        floatx4 uv0 = *(const floatx4*)(wrow + 1024);
        floatx4 uv1 = *(const floatx4*)(wrow + 1028);
        floatx4 fc0 = (floatx4){0.f,0.f,0.f,0.f};
        floatx4 fc1 = (floatx4){0.f,0.f,0.f,0.f};
        if (hasU) {
            const float* drow = ioud + (size_t)t * 1536 + j8;
            iv0 += *(const floatx4*)(drow);        iv1 += *(const floatx4*)(drow + 4);
            ov0 += *(const floatx4*)(drow + 512);  ov1 += *(const floatx4*)(drow + 516);
            uv0 += *(const floatx4*)(drow + 1024); uv1 += *(const floatx4*)(drow + 1028);
            const float* wfp = wx_f + (size_t)n * 512 + j8;
            floatx4 wf0 = *(const floatx4*)(wfp);
            floatx4 wf1 = *(const floatx4*)(wfp + 4);
            #pragma unroll
            for (int q = 0; q < 4; ++q) {
                const float* fp = fd + (size_t)(4 * t + q) * 512 + j8;
                const float* cp = c_child + (size_t)(4 * t + q) * 512 + j8;
                floatx4 f0 = *(const floatx4*)(fp),  f1 = *(const floatx4*)(fp + 4);
                floatx4 cv0 = *(const floatx4*)(cp), cv1 = *(const floatx4*)(cp + 4);
                fc0 += (wf0 + f0) * cv0;
                fc1 += (wf1 + f1) * cv1;
            }
        }
        floatx4 cn0, cn1, hn0, hn1;
        #pragma unroll
        for (int c = 0; c < 4; ++c) {
            float ig = 1.f / (1.f + expf(-iv0[c]));
            float og = 1.f / (1.f + expf(-ov0[c]));
            float ug = tanhf(uv0[c]);
            float cv2 = ig * ug + fc0[c];
            cn0[c] = cv2;
            hn0[c] = og * tanhf(cv2);
        }
        #pragma unroll
        for (int c = 0; c < 4; ++c) {
            float ig = 1.f / (1.f + expf(-iv1[c]));
            float og = 1.f / (1.f + expf(-ov1[c]));
            float ug = tanhf(uv1[c]);
            float cv2 = ig * ug + fc1[c];
            cn1[c] = cv2;
            hn1[c] = og * tanhf(cv2);
        }
        float* cop = c_out + (size_t)n * 512 + j8;
        float* hop = h_out + (size_t)n * 512 + j8;
        *(floatx4*)(cop)     = cn0;  *(floatx4*)(cop + 4) = cn1;
        *(floatx4*)(hop)     = hn0;  *(floatx4*)(hop + 4) = hn1;
        ushort4 hb0, hb1;
        hb0.x = f2bf(hn0[0]); hb0.y = f2bf(hn0[1]); hb0.z = f2bf(hn0[2]); hb0.w = f2bf(hn0[3]);
        hb1.x = f2bf(hn1[0]); hb1.y = f2bf(hn1[1]); hb1.z = f2bf(hn1[2]); hb1.w = f2bf(hn1[3]);
        *(ushort4*)(h_bf + (size_t)n * 512 + j8)     = hb0;
        *(ushort4*)(h_bf + (size_t)n * 512 + j8 + 4) = hb1;

        hsbuf[k * 128 + jg * 2]     = hn0;
        hsbuf[k * 128 + jg * 2 + 1] = hn1;
        __syncthreads();
        if (threadIdx.x < 64) {
            const int g = threadIdx.x;
            floatx4 s0 = hsbuf[g*2]   + hsbuf[128 + g*2]   + hsbuf[256 + g*2]   + hsbuf[384 + g*2];
            floatx4 s1 = hsbuf[g*2+1] + hsbuf[128 + g*2+1] + hsbuf[256 + g*2+1] + hsbuf[384 + g*2+1];
            ushort4 o0, o1;
            o0.x = f2bf(s0[0]); o0.y = f2bf(s0[1]); o0.z = f2bf(s0[2]); o0.w = f2bf(s0[3]);
            o1.x = f2bf(s1[0]); o1.y = f2bf(s1[1]); o1.z = f2bf(s1[2]); o1.w = f2bf(s1[3]);
            *(ushort4*)(hs_bf + (size_t)tp * 512 + g * 8)     = o0;
            *(ushort4*)(hs_bf + (size_t)tp * 512 + g * 8 + 4) = o1;
        }
        __syncthreads();
    }
}

// ================= phase kernels =================
__global__ __launch_bounds__(256) void wgemm_kernel(
    const unsigned short* __restrict__ xb,
    const unsigned short* __restrict__ Wib,
    const unsigned short* __restrict__ Wfb,
    const float* __restrict__ b_iou, const float* __restrict__ b_f,
    float* __restrict__ wx_iou, float* __restrict__ wx_f)
{
    int b = blockIdx.x;
    if (b < 516) {
        gemm_tile_128(xb, N_INT, Wib, b_iou, wx_iou, 1536, (b / 12) * 128, (b % 12) * 128);
    } else {
        int b2 = b - 516;
        gemm_tile_128(xb, 1365, Wfb, b_f, wx_f, 512, (b2 / 4) * 128, (b2 % 4) * 128);
    }
}

__global__ __launch_bounds__(256) void gemm5_kernel(
    const unsigned short* __restrict__ hs_bf,
    const unsigned short* __restrict__ h6_bf,
    const unsigned short* __restrict__ Uib, const unsigned short* __restrict__ Ufb,
    float* __restrict__ ioud, float* __restrict__ fd)
{
    int b = blockIdx.x;
    if (b < 96) {
        gemm_tile_128(hs_bf, 1024, Uib, nullptr, ioud, 1536, (b / 12) * 128, (b % 12) * 128);
    } else {
        int b2 = b - 96;
        gemm_tile_128(h6_bf, 4096, Ufb, nullptr, fd, 512, (b2 / 4) * 128, (b2 % 4) * 128);
    }
}

__global__ __launch_bounds__(256) void combine_kernel_fb(
    const float* __restrict__ wx_iou, const float* __restrict__ wx_f,
    const float* __restrict__ ioud, const float* __restrict__ fd,
    const float* __restrict__ c_child,
    float* __restrict__ h_out, float* __restrict__ c_out,
    unsigned short* __restrict__ h_bf, unsigned short* __restrict__ hs_bf,
    int s, int np, int hasU)
{
    combine_level_256(wx_iou, wx_f, ioud, fd, c_child, h_out, c_out, h_bf, hs_bf,
                      s, np, hasU, (int)gridDim.x);
}

// ---- P56 cooperative: gemm4 (56 jobs) + 64-block barrier + combine4 (validated r5) ----
__global__ __launch_bounds__(256) void p56_kernel(
    unsigned short* hs_bf, const unsigned short* __restrict__ h5_bf,
    const unsigned short* __restrict__ Uib, const unsigned short* __restrict__ Ufb,
    float* ioud, float* fd,
    const float* __restrict__ wx_iou, const float* __restrict__ wx_f,
    float* c_out, float* h_out,
    unsigned short* h_bf,
    unsigned* bar)
{
    if (blockIdx.x < 56) {
        int b = blockIdx.x;
        if (b < 24)
            gemm_tile_128(hs_bf, 256, Uib, nullptr, ioud, 1536, (b / 12) * 128, (b % 12) * 128);
        else {
            int b2 = b - 24;
            gemm_tile_128(h5_bf, 1024, Ufb, nullptr, fd, 512, (b2 / 4) * 128, (b2 % 4) * 128);
        }
    }
    grid_bar(bar, 1);   // 64 arrivals: cheap regime
    combine_level_256(wx_iou, wx_f, ioud, fd, c_out + (size_t)341 * HID,
                      h_out, c_out, h_bf, hs_bf, 85, 64, 1, 64);
}

// ---- TAIL cooperative: 16 blocks, levels 3..1 + root (tail_bar x7). NO zeroing here
//      (round-5 lesson: 67 MB of streaming writes on a narrow grid ran at 0.7 TB/s
//      and was the 101us long pole; zeroing now lives in wide-grid prep). ----
__global__ __launch_bounds__(256) void tail_kernel(
    unsigned short* hs_bf, unsigned short* h_bf,
    const unsigned short* __restrict__ Uib, const unsigned short* __restrict__ Ufb,
    float* ioud, float* fd,
    const float* __restrict__ wx_iou, const float* __restrict__ wx_f,
    float* h_out, float* c_out,
    unsigned* bar)
{
    small_gemm_phase(hs_bf, h_bf + (size_t)85 * HID, Uib, Ufb, ioud, fd, 64, 16);
    tail_bar(bar, 1);
    combine_level_256(wx_iou, wx_f, ioud, fd, c_out + (size_t)85 * HID,
                      h_out, c_out, h_bf, hs_bf, 21, 16, 1, 16);
    tail_bar(bar, 2);
    small_gemm_phase(hs_bf, h_bf + (size_t)21 * HID, Uib, Ufb, ioud, fd, 16, 16);
    tail_bar(bar, 3);
    combine_level_256(wx_iou, wx_f, ioud, fd, c_out + (size_t)21 * HID,
                      h_out, c_out, h_bf, hs_bf, 5, 4, 1, 16);
    tail_bar(bar, 4);
    small_gemm_phase(hs_bf, h_bf + (size_t)5 * HID, Uib, Ufb, ioud, fd, 4, 16);
    tail_bar(bar, 5);
    combine_level_256(wx_iou, wx_f, ioud, fd, c_out + (size_t)5 * HID,
                      h_out, c_out, h_bf, hs_bf, 1, 1, 1, 16);
    tail_bar(bar, 6);
    small_gemm_phase(hs_bf, h_bf + (size_t)1 * HID, Uib, Ufb, ioud, fd, 1, 16);
    tail_bar(bar, 7);
    if (blockIdx.x == 0) {
        const int j = threadIdx.x * 2;
        #pragma unroll
        for (int c = 0; c < 2; ++c) {
            const int jj = j + c;
            float iv = wx_iou[jj]        + ioud[jj];
            float ov = wx_iou[512 + jj]  + ioud[512 + jj];
            float uv = wx_iou[1024 + jj] + ioud[1024 + jj];
            float wf = wx_f[jj];
            float fc = 0.f;
            #pragma unroll
            for (int q = 0; q < 4; ++q)
                fc += (wf + fd[(size_t)q * 512 + jj]) * c_out[(size_t)(q + 1) * 512 + jj];
            float ig = 1.f / (1.f + expf(-iv));
            float og = 1.f / (1.f + expf(-ov));
            float ug = tanhf(uv);
            float cv2 = ig * ug + fc;
            c_out[jj] = cv2;
            h_out[jj] = og * tanhf(cv2);
        }
    }
}

// ================= fallback-only kernels =================
__global__ __launch_bounds__(256) void gemm4_kernel(
    const unsigned short* __restrict__ hs_bf,
    const unsigned short* __restrict__ h5_bf,
    const unsigned short* __restrict__ Uib, const unsigned short* __restrict__ Ufb,
    float* __restrict__ ioud, float* __restrict__ fd)
{
    int b = blockIdx.x;
    if (b < 24) {
        gemm_tile_128(hs_bf, 256, Uib, nullptr, ioud, 1536, (b / 12) * 128, (b % 12) * 128);
    } else {
        int b2 = b - 24;
        gemm_tile_128(h5_bf, 1024, Ufb, nullptr, fd, 512, (b2 / 4) * 128, (b2 % 4) * 128);
    }
}

__global__ __launch_bounds__(256) void gemm_small_kernel(
    const unsigned short* __restrict__ hs_bf,
    const unsigned short* __restrict__ hch_bf,
    const unsigned short* __restrict__ Uib, const unsigned short* __restrict__ Ufb,
    float* __restrict__ ioud, float* __restrict__ fd, int nl)
{
    const int w = blockIdx.x * 4 + (threadIdx.x >> 6);
    const int mI = (nl + 15) >> 4;
    const int mF = (4 * nl + 15) >> 4;
    if (w < mI * 24) {
        direct_tile_16x64(hs_bf, nl, Uib, ioud, 1536, (w / 24) * 16, (w % 24) * 64);
    } else {
        int w2 = w - mI * 24;
        if (w2 < mF * 8)
            direct_tile_16x64(hch_bf, 4 * nl, Ufb, fd, 512, (w2 / 8) * 16, (w2 % 8) * 64);
    }
}

__global__ __launch_bounds__(128) void combine_root_kernel(
    const float* __restrict__ wx_iou, const float* __restrict__ wx_f,
    const float* __restrict__ ioud, const float* __restrict__ fd,
    const float* __restrict__ c_child,
    float* __restrict__ h_out, float* __restrict__ c_out)
{
    const int j4 = threadIdx.x << 2;
    #pragma unroll
    for (int c = 0; c < 4; ++c) {
        const int jj = j4 + c;
        float iv = wx_iou[jj]        + ioud[jj];
        float ov = wx_iou[512 + jj]  + ioud[512 + jj];
        float uv = wx_iou[1024 + jj] + ioud[1024 + jj];
        float wf = wx_f[jj];
        float fc = 0.f;
        #pragma unroll
        for (int q = 0; q < 4; ++q)
            fc += (wf + fd[(size_t)q * 512 + jj]) * c_child[(size_t)q * 512 + jj];
        float ig = 1.f / (1.f + expf(-iv));
        float og = 1.f / (1.f + expf(-ov));
        float ug = tanhf(uv);
        float cv2 = ig * ug + fc;
        c_out[jj] = cv2;
        h_out[jj] = og * tanhf(cv2);
    }
}

extern "C" void kernel_launch(void* const* d_in, const int* in_sizes, int n_in,
                              void* d_out, int out_size, void* d_ws, size_t ws_size,
                              hipStream_t stream) {
    const float* x     = (const float*)d_in[0];
    // d_in[1] = children: deterministic (4n+1..4n+4), not needed
    const float* W_iou = (const float*)d_in[2];
    const float* b_iou = (const float*)d_in[3];
    const float* W_f   = (const float*)d_in[4];
    const float* b_f   = (const float*)d_in[5];
    const float* U_iou = (const float*)d_in[6];
    const float* U_f   = (const float*)d_in[7];

    float* h_out = (float*)d_out;                       // N_NODES x 512
    float* c_out = h_out + (size_t)N_NODES * HID;       // N_NODES x 512

    // ---- workspace layout (fp32 region, then contiguous bf16 cast region) ----
    float* ws     = (float*)d_ws;
    float* wx_iou = ws;                                  // 5461*1536 f32
    float* wx_f   = wx_iou + (size_t)N_INT * 1536;       // 1365*512  f32
    float* ioud   = wx_f   + (size_t)1365 * 512;         // 1024*1536 f32
    float* fd     = ioud   + (size_t)1024 * 1536;        // 4096*512  f32
    unsigned short* xb   = (unsigned short*)(fd + (size_t)4096 * 512);
    unsigned short* Wib  = xb  + (size_t)N_INT * 512;    // 1536*512 bf16
    unsigned short* Wfb  = Wib + (size_t)1536 * 512;     // 512*512
    unsigned short* Uib  = Wfb + (size_t)512 * 512;      // 1536*512
    unsigned short* Ufb  = Uib + (size_t)1536 * 512;     // 512*512
    unsigned short* h_bf = Ufb + (size_t)512 * 512;      // 5461*512
    unsigned short* hs_bf= h_bf + (size_t)N_INT * 512;   // 1024*512
    unsigned* bar = (unsigned*)(hs_bf + (size_t)1024 * 512);  // barrier lines (~8.6 KB)

    static int coopOK = -1;   // -1 unknown, 0 broken, 1 works

    // ---- dispatch 0: barrier counters (ws re-poisoned each iteration) ----
    bool barReady = false;
    if (coopOK != 0) {
        barReady = (hipMemsetAsync(bar, 0, 8704, stream) == hipSuccess);
        if (!barReady) { coopOK = 0; (void)hipGetLastError(); }
    }

    // ---- wide phases: plain dispatches (boundary ~5-7us < wide-barrier ~35us) ----
    prep_kernel<<<2048, 256, 0, stream>>>(x, W_iou, W_f, U_iou, U_f,
                                          h_out + (size_t)N_INT * HID,
                                          c_out + (size_t)N_INT * HID, xb);
    wgemm_kernel<<<560, 256, 0, stream>>>(xb, Wib, Wfb, b_iou, b_f, wx_iou, wx_f);
    combine_kernel_fb<<<1024, 256, 0, stream>>>(
        wx_iou, nullptr, nullptr, nullptr, nullptr,
        h_out, c_out, h_bf, hs_bf, 1365, 1024, 0);
    gemm5_kernel<<<224, 256, 0, stream>>>(hs_bf, h_bf + (size_t)1365 * HID, Uib, Ufb, ioud, fd);
    combine_kernel_fb<<<256, 256, 0, stream>>>(
        wx_iou, wx_f, ioud, fd, c_out + (size_t)1365 * HID,
        h_out, c_out, h_bf, hs_bf, 341, 256, 1);

    // ---- narrow phases: in-kernel barriers (cheap at <=64 arrivals) ----
    bool p56done = false, taildone = false;
    if (coopOK != 0 && barReady) {
        const unsigned short* h5_bf = h_bf + (size_t)341 * HID;
        void* a1[] = { (void*)&hs_bf, (void*)&h5_bf, (void*)&Uib, (void*)&Ufb,
                       (void*)&ioud, (void*)&fd, (void*)&wx_iou, (void*)&wx_f,
                       (void*)&c_out, (void*)&h_out, (void*)&h_bf, (void*)&bar };
        if (hipLaunchCooperativeKernel((const void*)p56_kernel,
                                       dim3(64), dim3(256), a1, 0, stream) == hipSuccess) {
            p56done = true;
            void* a2[] = { (void*)&hs_bf, (void*)&h_bf, (void*)&Uib, (void*)&Ufb,
                           (void*)&ioud, (void*)&fd, (void*)&wx_iou, (void*)&wx_f,
                           (void*)&h_out, (void*)&c_out, (void*)&bar };
            if (hipLaunchCooperativeKernel((const void*)tail_kernel,
                                           dim3(16), dim3(256), a2, 0, stream) == hipSuccess) {
                taildone = true;
                coopOK = 1;
            } else {
                coopOK = 0; (void)hipGetLastError();
            }
        } else {
            coopOK = 0; (void)hipGetLastError();
        }
    }

    if (!p56done) {
        gemm4_kernel<<<56, 256, 0, stream>>>(hs_bf, h_bf + (size_t)341 * HID, Uib, Ufb, ioud, fd);
        combine_kernel_fb<<<64, 256, 0, stream>>>(
            wx_iou, wx_f, ioud, fd, c_out + (size_t)341 * HID,
            h_out, c_out, h_bf, hs_bf, 85, 64, 1);
    }
    if (!taildone) {
        const int offs[9] = {0, 1, 5, 21, 85, 341, 1365, 5461, 21845};
        for (int l = 3; l >= 1; --l) {
            const int s  = offs[l];
            const int nl = offs[l + 1] - s;
            const int cb = offs[l + 1];
            const int mI = (nl + 15) >> 4;
            const int mF = (4 * nl + 15) >> 4;
            const int waves = mI * 24 + mF * 8;
            gemm_small_kernel<<<(waves + 3) / 4, 256, 0, stream>>>(
                hs_bf, h_bf + (size_t)cb * HID, Uib, Ufb, ioud, fd, nl);
            combine_kernel_fb<<<(nl + 3) / 4, 256, 0, stream>>>(
                wx_iou, wx_f, ioud, fd, c_out + (size_t)cb * HID,
                h_out, c_out, h_bf, hs_bf, s, nl >> 2, 1);
        }
        gemm_small_kernel<<<8, 256, 0, stream>>>(
            hs_bf, h_bf + (size_t)1 * HID, Uib, Ufb, ioud, fd, 1);
        combine_root_kernel<<<1, 128, 0, stream>>>(
            wx_iou, wx_f, ioud, fd, c_out + (size_t)1 * HID, h_out, c_out);
    }
}